// Round 8
// baseline (962.649 us; speedup 1.0000x reference)
//
#include <hip/hip_runtime.h>
#include <math.h>

#define Bz 4
#define Tz 4096
#define Dz 1024
#define Hz 16
#define HDz 64
#define BHz 64
#define Mz 16384

typedef __attribute__((ext_vector_type(8))) short short8;
typedef __attribute__((ext_vector_type(8))) __bf16 bf16x8;
typedef __attribute__((ext_vector_type(4))) float floatx4;

__device__ inline unsigned short f2bf(float f) {
    unsigned u = __float_as_uint(f);
    u = (u + 0x7fffu + ((u >> 16) & 1u)) >> 16;   // RNE; finite data only
    return (unsigned short)u;
}
__device__ inline float bf2f(unsigned short h) {
    return __uint_as_float(((unsigned)h) << 16);
}

// async global->LDS 16B DMA; LDS dest must be wave-linear (base + lane*16)
__device__ __forceinline__ void g2l16(const void* g, void* l) {
    __builtin_amdgcn_global_load_lds(
        (const __attribute__((address_space(1))) unsigned int*)g,
        (__attribute__((address_space(3))) unsigned int*)l,
        16, 0, 0);
}

// ---------------- trig table (one (t,j) pair per thread) ----------------
__global__ __launch_bounds__(256) void k_trig(float* __restrict__ tbl) {
    int gid = blockIdx.x * 256 + threadIdx.x;   // 0..262143
    int t = gid >> 6;
    int j = gid & 63;
    int kidx = (j < 32) ? j : (j - 32);
    double e = (double)(2 * kidx) / 64.0;
    float p = (float)pow(10000.0, e);
    float invf = 1.0f / p;
    float arg = (float)t * invf;
    tbl[t * 128 + j * 2 + 0] = cosf(arg);
    tbl[t * 128 + j * 2 + 1] = sinf(arg);
}

// ---------------- split fp32 x -> bf16 3 levels ----------------
__global__ __launch_bounds__(256) void k_cvtA(const float* __restrict__ x,
                                              unsigned short* __restrict__ xh,
                                              unsigned short* __restrict__ xl,
                                              unsigned short* __restrict__ xll)
{
    size_t i4 = (size_t)blockIdx.x * 256 + threadIdx.x;
    float4 v = *(const float4*)(x + i4 * 4);
    ushort4 h, l, l2;
    float r;
    h.x = f2bf(v.x); r = v.x - bf2f(h.x); l.x = f2bf(r); l2.x = f2bf(r - bf2f(l.x));
    h.y = f2bf(v.y); r = v.y - bf2f(h.y); l.y = f2bf(r); l2.y = f2bf(r - bf2f(l.y));
    h.z = f2bf(v.z); r = v.z - bf2f(h.z); l.z = f2bf(r); l2.z = f2bf(r - bf2f(l.z));
    h.w = f2bf(v.w); r = v.w - bf2f(h.w); l.w = f2bf(r); l2.w = f2bf(r - bf2f(l.w));
    *(ushort4*)(xh  + i4 * 4) = h;
    *(ushort4*)(xl  + i4 * 4) = l;
    *(ushort4*)(xll + i4 * 4) = l2;
}

// ---------------- transpose+split W_attn K/V cols (2-level) ----------------
__global__ __launch_bounds__(256) void k_cvtB(const float* __restrict__ W,
                                              unsigned short* __restrict__ wh,
                                              unsigned short* __restrict__ wl)
{
    __shared__ float tile[64][65];
    const int n0 = blockIdx.x * 64;
    const int k0 = blockIdx.y * 64;
    const int tid = threadIdx.x;
#pragma unroll
    for (int i = 0; i < 16; ++i) {
        int flat = i * 256 + tid;
        int kr = flat >> 6, nc = flat & 63;
        tile[kr][nc] = W[(size_t)(k0 + kr) * 3072 + 1024 + n0 + nc];
    }
    __syncthreads();
#pragma unroll
    for (int i = 0; i < 16; ++i) {
        int flat = i * 256 + tid;
        int nr = flat >> 6, kc = flat & 63;
        float v = tile[kc][nr];
        unsigned short h = f2bf(v);
        wh[(size_t)(n0 + nr) * 1024 + k0 + kc] = h;
        wl[(size_t)(n0 + nr) * 1024 + k0 + kc] = f2bf(v - bf2f(h));
    }
}

// ---------------- transpose+split W_attn Q cols (3-level) ----------------
__global__ __launch_bounds__(256) void k_cvtBQ(const float* __restrict__ W,
                                               unsigned short* __restrict__ wh,
                                               unsigned short* __restrict__ wl,
                                               unsigned short* __restrict__ wll)
{
    __shared__ float tile[64][65];
    const int n0 = blockIdx.x * 64;
    const int k0 = blockIdx.y * 64;
    const int tid = threadIdx.x;
#pragma unroll
    for (int i = 0; i < 16; ++i) {
        int flat = i * 256 + tid;
        int kr = flat >> 6, nc = flat & 63;
        tile[kr][nc] = W[(size_t)(k0 + kr) * 3072 + n0 + nc];
    }
    __syncthreads();
#pragma unroll
    for (int i = 0; i < 16; ++i) {
        int flat = i * 256 + tid;
        int nr = flat >> 6, kc = flat & 63;
        float v = tile[kc][nr];
        unsigned short h = f2bf(v);
        float r1 = v - bf2f(h);
        unsigned short l = f2bf(r1);
        wh [(size_t)(n0 + nr) * 1024 + k0 + kc] = h;
        wl [(size_t)(n0 + nr) * 1024 + k0 + kc] = l;
        wll[(size_t)(n0 + nr) * 1024 + k0 + kc] = f2bf(r1 - bf2f(l));
    }
}

// ---------------- transpose+split W_proj ----------------
__global__ __launch_bounds__(256) void k_cvtP(const float* __restrict__ W,
                                              unsigned short* __restrict__ wh,
                                              unsigned short* __restrict__ wl)
{
    __shared__ float tile[64][65];
    const int n0 = blockIdx.x * 64;
    const int k0 = blockIdx.y * 64;
    const int tid = threadIdx.x;
#pragma unroll
    for (int i = 0; i < 16; ++i) {
        int flat = i * 256 + tid;
        int kr = flat >> 6, nc = flat & 63;
        tile[kr][nc] = W[(size_t)(k0 + kr) * 1024 + n0 + nc];
    }
    __syncthreads();
#pragma unroll
    for (int i = 0; i < 16; ++i) {
        int flat = i * 256 + tid;
        int nr = flat >> 6, kc = flat & 63;
        float v = tile[kc][nr];
        unsigned short h = f2bf(v);
        wh[(size_t)(n0 + nr) * 1024 + k0 + kc] = h;
        wl[(size_t)(n0 + nr) * 1024 + k0 + kc] = f2bf(v - bf2f(h));
    }
}

// ---------------- Q via 6-term split-bf16 MFMA, 256x128 tile, 2-pass ------
// pass1: terms {00,01,10,11} on (xh,xl)x(wqh,wql); pass2: {02,20} on
// (xh,xll)x(wqh,wll).  Accumulation order identical to the round-5-verified
// 2-pass kernel.  8 waves, LDS 48KB.
__global__ __launch_bounds__(512) void k_q6(const unsigned short* __restrict__ xh,
                                            const unsigned short* __restrict__ xl,
                                            const unsigned short* __restrict__ xll,
                                            const unsigned short* __restrict__ wh,
                                            const unsigned short* __restrict__ wl,
                                            const unsigned short* __restrict__ wll,
                                            const float* __restrict__ bias,
                                            const float* __restrict__ tbl,
                                            float* __restrict__ Qb)
{
    __shared__ unsigned short A0s[256 * 32], A1s[256 * 32];
    __shared__ unsigned short B0s[128 * 32], B1s[128 * 32];
    const int tid = threadIdx.x;
    const int lane = tid & 63, wv = tid >> 6;
    const int hw = blockIdx.y * 8 + blockIdx.x;      // nwg = 512
    const int lg = (hw & 7) * 64 + (hw >> 3);        // bijective XCD-chunk
    const int n0 = (lg & 7) * 128;
    const int m0 = (lg >> 3) * 256;
    const int wm = (wv & 3) * 64, wn = (wv >> 2) * 64;
    const int sra = tid >> 2, sca = tid & 3;
    const int fr = lane & 15, fq = lane >> 4;

    floatx4 acc[4][4];
#pragma unroll
    for (int i = 0; i < 4; ++i)
#pragma unroll
        for (int j = 0; j < 4; ++j) acc[i][j] = (floatx4){0.f, 0.f, 0.f, 0.f};

    auto stage = [&](const unsigned short* a1, const unsigned short* b1, int kt) {
#pragma unroll
        for (int s = 0; s < 2; ++s) {
            int row = s * 128 + sra;
            size_t ga = (size_t)(m0 + row) * 1024 + kt + sca * 8;
            int lo = row * 32 + sca * 8;
            g2l16(xh + ga, &A0s[lo]);
            g2l16(a1 + ga, &A1s[lo]);
        }
        int rb = sra;                                 // 0..127
        size_t gb = (size_t)(n0 + rb) * 1024 + kt + sca * 8;
        int lb_ = rb * 32 + sca * 8;
        g2l16(wh + gb, &B0s[lb_]);
        g2l16(b1 + gb, &B1s[lb_]);
    };

    for (int pass = 0; pass < 2; ++pass) {
        const unsigned short* a1 = pass ? xll : xl;
        const unsigned short* b1 = pass ? wll : wl;
        for (int kt = 0; kt < 1024; kt += 32) {
            __syncthreads();
            stage(a1, b1, kt);
            __syncthreads();

            bf16x8 a0[4], a1f[4];
#pragma unroll
            for (int i = 0; i < 4; ++i) {
                a0[i]  = __builtin_bit_cast(bf16x8, *(const short8*)(&A0s[(wm + i * 16 + fr) * 32 + fq * 8]));
                a1f[i] = __builtin_bit_cast(bf16x8, *(const short8*)(&A1s[(wm + i * 16 + fr) * 32 + fq * 8]));
            }
#pragma unroll
            for (int j = 0; j < 4; ++j) {
                bf16x8 b0 = __builtin_bit_cast(bf16x8, *(const short8*)(&B0s[(wn + j * 16 + fr) * 32 + fq * 8]));
                bf16x8 b1f = __builtin_bit_cast(bf16x8, *(const short8*)(&B1s[(wn + j * 16 + fr) * 32 + fq * 8]));
#pragma unroll
                for (int i = 0; i < 4; ++i) {
                    if (pass == 0) {
                        acc[i][j] = __builtin_amdgcn_mfma_f32_16x16x32_bf16(a0[i],  b0,  acc[i][j], 0, 0, 0);
                        acc[i][j] = __builtin_amdgcn_mfma_f32_16x16x32_bf16(a0[i],  b1f, acc[i][j], 0, 0, 0);
                        acc[i][j] = __builtin_amdgcn_mfma_f32_16x16x32_bf16(a1f[i], b0,  acc[i][j], 0, 0, 0);
                        acc[i][j] = __builtin_amdgcn_mfma_f32_16x16x32_bf16(a1f[i], b1f, acc[i][j], 0, 0, 0);
                    } else {
                        acc[i][j] = __builtin_amdgcn_mfma_f32_16x16x32_bf16(a0[i],  b1f, acc[i][j], 0, 0, 0);
                        acc[i][j] = __builtin_amdgcn_mfma_f32_16x16x32_bf16(a1f[i], b0,  acc[i][j], 0, 0, 0);
                    }
                }
            }
        }
    }

    // epilogue: bias + rope, scatter to Qb (all cols are Q)
#pragma unroll
    for (int j = 0; j < 4; ++j) {
        int nn = n0 + wn + j * 16 + fr;
        float bv = bias[nn];
        int h = nn >> 6, d = nn & 63;
#pragma unroll
        for (int i = 0; i < 4; ++i) {
#pragma unroll
            for (int r = 0; r < 4; ++r) {
                int mm = m0 + wm + i * 16 + fq * 4 + r;
                int t = mm & 4095, bb = mm >> 12;
                float y = acc[i][j][r] + bv;
                float part = __shfl_xor(y, 1);
                float c = tbl[t * 128 + d * 2];
                float s = tbl[t * 128 + d * 2 + 1];
                float o = (d & 1) ? fmaf(part, s, y * c) : fmaf(-part, s, y * c);
                Qb[((size_t)(bb * 16 + h) * 4096 + t) * 64 + d] = o;
            }
        }
    }
}

// ---------------- K,V via split-bf16 MFMA, 256x128 tile, 8 waves ---------
__global__ __launch_bounds__(512) void k_kv(const unsigned short* __restrict__ xh,
                                            const unsigned short* __restrict__ xl,
                                            const unsigned short* __restrict__ wh,
                                            const unsigned short* __restrict__ wl,
                                            const float* __restrict__ bias,
                                            const float* __restrict__ tbl,
                                            float* __restrict__ Kb,
                                            float* __restrict__ Vb)
{
    __shared__ unsigned short Ah[256 * 32], Al[256 * 32];
    __shared__ unsigned short Bh[128 * 32], Bl[128 * 32];
    const int tid = threadIdx.x;
    const int lane = tid & 63, wv = tid >> 6;
    const int hw = blockIdx.y * 8 + blockIdx.x;      // nwg = 1024
    const int lg = (hw & 7) * 128 + (hw >> 3);       // bijective XCD-chunk
    const int n0 = (lg & 15) * 128;
    const int m0 = (lg >> 4) * 256;
    const int wm = (wv & 3) * 64, wn = (wv >> 2) * 64;
    const int sra = tid >> 2, sca = tid & 3;
    const int fr = lane & 15, fq = lane >> 4;

    floatx4 acc[4][4];
#pragma unroll
    for (int i = 0; i < 4; ++i)
#pragma unroll
        for (int j = 0; j < 4; ++j) acc[i][j] = (floatx4){0.f, 0.f, 0.f, 0.f};

    for (int kt = 0; kt < 1024; kt += 32) {
        __syncthreads();
#pragma unroll
        for (int s = 0; s < 2; ++s) {
            int row = s * 128 + sra;
            size_t ga = (size_t)(m0 + row) * 1024 + kt + sca * 8;
            int lo = row * 32 + sca * 8;
            g2l16(xh + ga, &Ah[lo]);
            g2l16(xl + ga, &Al[lo]);
        }
        {
            int rb = sra;                             // 0..127
            size_t gb = (size_t)(n0 + rb) * 1024 + kt + sca * 8;
            int lb_ = rb * 32 + sca * 8;
            g2l16(wh + gb, &Bh[lb_]);
            g2l16(wl + gb, &Bl[lb_]);
        }
        __syncthreads();

        bf16x8 afh[4], afl[4];
#pragma unroll
        for (int i = 0; i < 4; ++i) {
            afh[i] = __builtin_bit_cast(bf16x8, *(const short8*)(&Ah[(wm + i * 16 + fr) * 32 + fq * 8]));
            afl[i] = __builtin_bit_cast(bf16x8, *(const short8*)(&Al[(wm + i * 16 + fr) * 32 + fq * 8]));
        }
#pragma unroll
        for (int j = 0; j < 4; ++j) {
            bf16x8 bfh = __builtin_bit_cast(bf16x8, *(const short8*)(&Bh[(wn + j * 16 + fr) * 32 + fq * 8]));
            bf16x8 bfl = __builtin_bit_cast(bf16x8, *(const short8*)(&Bl[(wn + j * 16 + fr) * 32 + fq * 8]));
#pragma unroll
            for (int i = 0; i < 4; ++i) {
                acc[i][j] = __builtin_amdgcn_mfma_f32_16x16x32_bf16(afh[i], bfh, acc[i][j], 0, 0, 0);
                acc[i][j] = __builtin_amdgcn_mfma_f32_16x16x32_bf16(afh[i], bfl, acc[i][j], 0, 0, 0);
                acc[i][j] = __builtin_amdgcn_mfma_f32_16x16x32_bf16(afl[i], bfh, acc[i][j], 0, 0, 0);
            }
        }
    }

#pragma unroll
    for (int j = 0; j < 4; ++j) {
        int nn = n0 + wn + j * 16 + fr;
        float bv = bias[1024 + nn];
#pragma unroll
        for (int i = 0; i < 4; ++i) {
#pragma unroll
            for (int r = 0; r < 4; ++r) {
                int mm = m0 + wm + i * 16 + fq * 4 + r;
                int t = mm & 4095, bb = mm >> 12;
                float y = acc[i][j][r] + bv;
                if (nn < 1024) {
                    int h = nn >> 6, d = nn & 63;
                    float part = __shfl_xor(y, 1);
                    float c = tbl[t * 128 + d * 2];
                    float s = tbl[t * 128 + d * 2 + 1];
                    float o = (d & 1) ? fmaf(part, s, y * c) : fmaf(-part, s, y * c);
                    Kb[((size_t)(bb * 16 + h) * 4096 + t) * 64 + d] = o;
                } else {
                    int nv = nn - 1024;
                    int h = nv >> 6, d = nv & 63;
                    Vb[((size_t)(bb * 16 + h) * 4096 + t) * 64 + d] = y;
                }
            }
        }
    }
}

// ---------------- bucket argmax ----------------
__global__ __launch_bounds__(64) void k_bucket(const float* __restrict__ Q,
                                               const float* __restrict__ R,
                                               int* __restrict__ bidx)
{
    __shared__ float Qs[64][65];
    __shared__ float Rs[64][32];
    const int tid = threadIdx.x;
    const int g0 = blockIdx.x * 64;
    const int bh = g0 >> 12;
    const int t0 = g0 & 4095;
#pragma unroll
    for (int m = 0; m < 32; ++m) Rs[tid][m] = R[tid * 64 + m];
    const float* qbase = Q + ((size_t)bh * Tz + t0) * 64;
    for (int r = 0; r < 64; ++r) Qs[r][tid] = qbase[(size_t)r * 64 + tid];
    __syncthreads();

    float s[32];
#pragma unroll
    for (int m = 0; m < 32; ++m) s[m] = 0.f;
    for (int d = 0; d < 64; ++d) {
        float qd = Qs[tid][d];
#pragma unroll
        for (int m4 = 0; m4 < 8; ++m4) {
            float4 r4 = *(const float4*)(&Rs[d][m4 * 4]);
            s[m4 * 4 + 0] = fmaf(qd, r4.x, s[m4 * 4 + 0]);
            s[m4 * 4 + 1] = fmaf(qd, r4.y, s[m4 * 4 + 1]);
            s[m4 * 4 + 2] = fmaf(qd, r4.z, s[m4 * 4 + 2]);
            s[m4 * 4 + 3] = fmaf(qd, r4.w, s[m4 * 4 + 3]);
        }
    }
    float best = s[0];
    int bi = 0;
#pragma unroll
    for (int m = 1; m < 64; ++m) {
        float v = (m < 32) ? s[m] : -s[m - 32];
        if (v > best) { best = v; bi = m; }
    }
    bidx[g0 + tid] = bi;
}

// ---------------- stable counting sort, wave-parallel ballot ranking ------
__global__ __launch_bounds__(64) void k_sort(const int* __restrict__ bidx,
                                             int* __restrict__ sidx)
{
    __shared__ int lb[4096];      // keys, then reused as packed (k<<16)|off
    __shared__ int ls[4096];
    __shared__ int runTot[64];
    __shared__ int base[64];
    const int lane = threadIdx.x;
    const int bh = blockIdx.x;
    const int* brow = bidx + (size_t)bh * 4096;
    for (int i = lane; i < 4096; i += 64) lb[i] = brow[i];
    runTot[lane] = 0;
    // single-wave kernel: LDS ops of one wave execute in program order

    const unsigned long long lmask = (1ull << lane) - 1ull;
    for (int r = 0; r < 64; ++r) {
        int i = r * 64 + lane;
        int k = lb[i];
        unsigned long long m = ~0ull;
#pragma unroll
        for (int b = 0; b < 6; ++b) {
            unsigned long long bb = __ballot((k >> b) & 1);
            m &= ((k >> b) & 1) ? bb : ~bb;
        }
        int rank = __popcll(m & lmask);
        int before = runTot[k];              // all lanes read pre-update value
        lb[i] = (k << 16) | (before + rank); // pack key + local offset
        if (rank == 0) runTot[k] = before + __popcll(m);
    }
    // exclusive prefix over 64 buckets (lane b holds bucket b)
    int tot = runTot[lane];
    int run = tot;
#pragma unroll
    for (int off = 1; off < 64; off <<= 1) {
        int n = __shfl_up(run, off, 64);
        if (lane >= off) run += n;
    }
    base[lane] = run - tot;
    // scatter
    for (int r = 0; r < 64; ++r) {
        int i = r * 64 + lane;
        int v = lb[i];
        ls[base[v >> 16] + (v & 0xffff)] = i;
    }
    int* srow = sidx + (size_t)bh * 4096;
    for (int i = lane; i < 4096; i += 64) srow[i] = ls[i];
}

// ---------------- chunked attention via MFMA (m120 pattern) --------------
// LDS (ushort): Kh[128][72]@0, Kl[128][72]@9216 ; P[128][144] overlays @0 after S
//               Vt[64][144]@18432  (dim-major)   total 27648 us = 55296 B
__global__ __launch_bounds__(256) void k_attn(const float* __restrict__ Q,
                                              const float* __restrict__ Kg,
                                              const float* __restrict__ Vg,
                                              const int* __restrict__ sidx,
                                              unsigned short* __restrict__ AOh,
                                              unsigned short* __restrict__ AOl)
{
    __shared__ unsigned short smem[27648];
    unsigned short* KhS = smem;
    unsigned short* KlS = smem + 9216;
    unsigned short* PbS = smem;
    unsigned short* VtS = smem + 18432;

    // XCD-chunked swizzle: all 32 chunks of one bh land on one XCD (Q/K/V ~3MB -> L2)
    const int hw = blockIdx.y * 32 + blockIdx.x;     // nwg = 2048
    const int lg = (hw & 7) * 256 + (hw >> 3);
    const int ch = lg & 31;
    const int bh = lg >> 5;
    const int tid = threadIdx.x;
    const int lane = tid & 63;
    const int w = tid >> 6;
    const int c = lane & 15;   // frag row/col
    const int q = lane >> 4;   // quad
    const int* srow = sidx + (size_t)bh * Tz + ch * 128;

    // ---- stage K (bf16 hi/lo) and V^T (bf16) ----
    {
        const int r = tid >> 1;
        const int d0 = (tid & 1) * 32;
        int orig = srow[r];
        const float* kp = Kg + ((size_t)bh * Tz + orig) * 64 + d0;
        const float* vp = Vg + ((size_t)bh * Tz + orig) * 64 + d0;
#pragma unroll
        for (int j4 = 0; j4 < 8; ++j4) {
            float4 k4 = *(const float4*)(kp + j4 * 4);
            ushort4 h4, l4;
            h4.x = f2bf(k4.x); l4.x = f2bf(k4.x - bf2f(h4.x));
            h4.y = f2bf(k4.y); l4.y = f2bf(k4.y - bf2f(h4.y));
            h4.z = f2bf(k4.z); l4.z = f2bf(k4.z - bf2f(h4.z));
            h4.w = f2bf(k4.w); l4.w = f2bf(k4.w - bf2f(h4.w));
            *(ushort4*)(&KhS[r * 72 + d0 + j4 * 4]) = h4;
            *(ushort4*)(&KlS[r * 72 + d0 + j4 * 4]) = l4;
            float4 v4 = *(const float4*)(vp + j4 * 4);
            int db = d0 + j4 * 4;
            VtS[(db + 0) * 144 + r] = f2bf(v4.x);
            VtS[(db + 1) * 144 + r] = f2bf(v4.y);
            VtS[(db + 2) * 144 + r] = f2bf(v4.z);
            VtS[(db + 3) * 144 + r] = f2bf(v4.w);
        }
    }

    // ---- Q fragments from global into registers (bf16 hi/lo) ----
    bf16x8 qh[2][2], ql[2][2];
#pragma unroll
    for (int i = 0; i < 2; ++i) {
        int row = w * 32 + i * 16 + c;
        int orig = srow[row];
        const float* qp = Q + ((size_t)bh * Tz + orig) * 64 + q * 8;
#pragma unroll
        for (int kc = 0; kc < 2; ++kc) {
            float4 fa = *(const float4*)(qp + kc * 32);
            float4 fb = *(const float4*)(qp + kc * 32 + 4);
            float f[8] = {fa.x, fa.y, fa.z, fa.w, fb.x, fb.y, fb.z, fb.w};
            short8 hh, ll;
#pragma unroll
            for (int e = 0; e < 8; ++e) {
                unsigned short h = f2bf(f[e]);
                hh[e] = (short)h;
                ll[e] = (short)f2bf(f[e] - bf2f(h));
            }
            qh[i][kc] = __builtin_bit_cast(bf16x8, hh);
            ql[i][kc] = __builtin_bit_cast(bf16x8, ll);
        }
    }
    __syncthreads();

    // ---- S = Q K^T (3-term split) ----
    floatx4 accs[2][8];
#pragma unroll
    for (int i = 0; i < 2; ++i)
#pragma unroll
        for (int j = 0; j < 8; ++j) accs[i][j] = (floatx4){0.f, 0.f, 0.f, 0.f};

#pragma unroll
    for (int j = 0; j < 8; ++j) {
        int n = j * 16 + c;
        bf16x8 kbh[2], kbl[2];
#pragma unroll
        for (int kc = 0; kc < 2; ++kc) {
            kbh[kc] = __builtin_bit_cast(bf16x8, *(const short8*)(&KhS[n * 72 + kc * 32 + q * 8]));
            kbl[kc] = __builtin_bit_cast(bf16x8, *(const short8*)(&KlS[n * 72 + kc * 32 + q * 8]));
        }
#pragma unroll
        for (int i = 0; i < 2; ++i)
#pragma unroll
            for (int kc = 0; kc < 2; ++kc) {
                accs[i][j] = __builtin_amdgcn_mfma_f32_16x16x32_bf16(qh[i][kc], kbh[kc], accs[i][j], 0, 0, 0);
                accs[i][j] = __builtin_amdgcn_mfma_f32_16x16x32_bf16(qh[i][kc], kbl[kc], accs[i][j], 0, 0, 0);
                accs[i][j] = __builtin_amdgcn_mfma_f32_16x16x32_bf16(ql[i][kc], kbh[kc], accs[i][j], 0, 0, 0);
            }
    }

    // ---- softmax over rows (row = w*32 + i*16 + q*4 + r) ----
    float linv[2][4];
#pragma unroll
    for (int i = 0; i < 2; ++i) {
#pragma unroll
        for (int r = 0; r < 4; ++r) {
            float mm = -1e30f;
#pragma unroll
            for (int j = 0; j < 8; ++j) {
                float v = accs[i][j][r] * 0.125f;
                accs[i][j][r] = v;
                mm = fmaxf(mm, v);
            }
#pragma unroll
            for (int off = 1; off < 16; off <<= 1) mm = fmaxf(mm, __shfl_xor(mm, off));
            float ss = 0.f;
#pragma unroll
            for (int j = 0; j < 8; ++j) {
                float p = expf(accs[i][j][r] - mm);
                accs[i][j][r] = p;
                ss += p;
            }
#pragma unroll
            for (int off = 1; off < 16; off <<= 1) ss += __shfl_xor(ss, off);
            linv[i][r] = 1.0f / ss;
        }
    }
    __syncthreads();   // all K reads done; safe to overlay P

    // ---- write P (bf16) rows [w*32, w*32+32) ----
#pragma unroll
    for (int i = 0; i < 2; ++i)
#pragma unroll
        for (int j = 0; j < 8; ++j)
#pragma unroll
            for (int r = 0; r < 4; ++r)
                PbS[(w * 32 + i * 16 + q * 4 + r) * 144 + j * 16 + c] = f2bf(accs[i][j][r]);
    // own-rows only: no barrier needed (same-wave write->read ordering via lgkmcnt)

    // ---- O = P V ----
    floatx4 acco[2][4];
#pragma unroll
    for (int i = 0; i < 2; ++i)
#pragma unroll
        for (int jf = 0; jf < 4; ++jf) acco[i][jf] = (floatx4){0.f, 0.f, 0.f, 0.f};

#pragma unroll
    for (int kc = 0; kc < 4; ++kc) {
        bf16x8 pa[2];
#pragma unroll
        for (int i = 0; i < 2; ++i)
            pa[i] = __builtin_bit_cast(bf16x8, *(const short8*)(&PbS[(w * 32 + i * 16 + c) * 144 + kc * 32 + q * 8]));
#pragma unroll
        for (int jf = 0; jf < 4; ++jf) {
            bf16x8 vb = __builtin_bit_cast(bf16x8, *(const short8*)(&VtS[(jf * 16 + c) * 144 + kc * 32 + q * 8]));
            acco[0][jf] = __builtin_amdgcn_mfma_f32_16x16x32_bf16(pa[0], vb, acco[0][jf], 0, 0, 0);
            acco[1][jf] = __builtin_amdgcn_mfma_f32_16x16x32_bf16(pa[1], vb, acco[1][jf], 0, 0, 0);
        }
    }

    // ---- epilogue: normalize, split bf16, scatter-unsort ----
    const int bb = bh >> 4, hh = bh & 15;
#pragma unroll
    for (int i = 0; i < 2; ++i) {
#pragma unroll
        for (int r = 0; r < 4; ++r) {
            int row = w * 32 + i * 16 + q * 4 + r;
            int orig = srow[row];
            float inv = linv[i][r];
            size_t base = ((size_t)bb * 4096 + orig) * 1024 + hh * 64 + c;
#pragma unroll
            for (int jf = 0; jf < 4; ++jf) {
                float val = acco[i][jf][r] * inv;
                unsigned short h = f2bf(val);
                unsigned short l = f2bf(val - bf2f(h));
                AOh[base + jf * 16] = h;
                AOl[base + jf * 16] = l;
            }
        }
    }
}

// ---------------- output projection, 256x128 tile, 8 waves ----------------
__global__ __launch_bounds__(512) void k_proj(const unsigned short* __restrict__ ah,
                                              const unsigned short* __restrict__ al,
                                              const unsigned short* __restrict__ wh,
                                              const unsigned short* __restrict__ wl,
                                              const float* __restrict__ bias,
                                              float* __restrict__ Cout)
{
    __shared__ unsigned short Ah[256 * 32], Al[256 * 32];
    __shared__ unsigned short Bh[128 * 32], Bl[128 * 32];
    const int tid = threadIdx.x;
    const int lane = tid & 63, wv = tid >> 6;
    const int hw = blockIdx.y * 8 + blockIdx.x;      // nwg = 512
    const int lg = (hw & 7) * 64 + (hw >> 3);        // bijective XCD-chunk
    const int n0 = (lg & 7) * 128;
    const int m0 = (lg >> 3) * 256;
    const int wm = (wv & 3) * 64, wn = (wv >> 2) * 64;
    const int sra = tid >> 2, sca = tid & 3;
    const int fr = lane & 15, fq = lane >> 4;

    floatx4 acc[4][4];
#pragma unroll
    for (int i = 0; i < 4; ++i)
#pragma unroll
        for (int j = 0; j < 4; ++j) acc[i][j] = (floatx4){0.f, 0.f, 0.f, 0.f};

    for (int kt = 0; kt < 1024; kt += 32) {
        __syncthreads();
#pragma unroll
        for (int s = 0; s < 2; ++s) {
            int row = s * 128 + sra;
            size_t ga = (size_t)(m0 + row) * 1024 + kt + sca * 8;
            int lo = row * 32 + sca * 8;
            g2l16(ah + ga, &Ah[lo]);
            g2l16(al + ga, &Al[lo]);
        }
        {
            int rb = sra;
            size_t gb = (size_t)(n0 + rb) * 1024 + kt + sca * 8;
            int lb_ = rb * 32 + sca * 8;
            g2l16(wh + gb, &Bh[lb_]);
            g2l16(wl + gb, &Bl[lb_]);
        }
        __syncthreads();

        bf16x8 afh[4], afl[4];
#pragma unroll
        for (int i = 0; i < 4; ++i) {
            afh[i] = __builtin_bit_cast(bf16x8, *(const short8*)(&Ah[(wm + i * 16 + fr) * 32 + fq * 8]));
            afl[i] = __builtin_bit_cast(bf16x8, *(const short8*)(&Al[(wm + i * 16 + fr) * 32 + fq * 8]));
        }
#pragma unroll
        for (int j = 0; j < 4; ++j) {
            bf16x8 bfh = __builtin_bit_cast(bf16x8, *(const short8*)(&Bh[(wn + j * 16 + fr) * 32 + fq * 8]));
            bf16x8 bfl = __builtin_bit_cast(bf16x8, *(const short8*)(&Bl[(wn + j * 16 + fr) * 32 + fq * 8]));
#pragma unroll
            for (int i = 0; i < 4; ++i) {
                acc[i][j] = __builtin_amdgcn_mfma_f32_16x16x32_bf16(afh[i], bfh, acc[i][j], 0, 0, 0);
                acc[i][j] = __builtin_amdgcn_mfma_f32_16x16x32_bf16(afh[i], bfl, acc[i][j], 0, 0, 0);
                acc[i][j] = __builtin_amdgcn_mfma_f32_16x16x32_bf16(afl[i], bfh, acc[i][j], 0, 0, 0);
            }
        }
    }

#pragma unroll
    for (int j = 0; j < 4; ++j) {
        int nn = n0 + wn + j * 16 + fr;
        float bv = bias[nn];
#pragma unroll
        for (int i = 0; i < 4; ++i) {
#pragma unroll
            for (int r = 0; r < 4; ++r) {
                int mm = m0 + wm + i * 16 + fq * 4 + r;
                Cout[(size_t)mm * 1024 + nn] = acc[i][j][r] + bv;
            }
        }
    }
}

extern "C" void kernel_launch(void* const* d_in, const int* in_sizes, int n_in,
                              void* d_out, int out_size, void* d_ws, size_t ws_size,
                              hipStream_t stream)
{
    const float* x      = (const float*)d_in[0];
    const float* W_attn = (const float*)d_in[1];
    const float* b_attn = (const float*)d_in[2];
    const float* W_proj = (const float*)d_in[3];
    const float* b_proj = (const float*)d_in[4];
    const float* R      = (const float*)d_in[5];
    float* out = (float*)d_out;

    char* ws = (char*)d_ws;
    const size_t MB = 1024 * 1024;
    float*          tbl  = (float*)(ws);                    // 0-2 MB
    float*          Qb   = (float*)(ws + 2 * MB);           // 2-66 MB
    float*          Kb   = (float*)(ws + 66 * MB);          // 66-130 MB
    // Q-GEMM-only buffers alias the Kb region (consumed before k_kv writes Kb)
    unsigned short* xll  = (unsigned short*)(ws + 66 * MB); // 66-98 MB  (alias Kb)
    unsigned short* wqh  = (unsigned short*)(ws + 98 * MB); // 98-100 MB (alias Kb)
    unsigned short* wql  = (unsigned short*)(ws + 100 * MB);// 100-102 MB(alias Kb)
    unsigned short* wqll = (unsigned short*)(ws + 102 * MB);// 102-104 MB(alias Kb)
    unsigned short* xh   = (unsigned short*)(ws + 130 * MB);// 32 MB
    unsigned short* xl   = (unsigned short*)(ws + 162 * MB);// 32 MB
    unsigned short* AOh  = (unsigned short*)(ws + 130 * MB);// 32 MB (alias xh)
    unsigned short* AOl  = (unsigned short*)(ws + 162 * MB);// 32 MB (alias xl)
    int*            bidx = (int*)(ws + 194 * MB);           // 1 MB
    int*            sidx = (int*)(ws + 195 * MB);           // 1 MB
    unsigned short* wth  = (unsigned short*)(ws + 196 * MB);// 4 MB
    unsigned short* wtl  = (unsigned short*)(ws + 200 * MB);// 4 MB
    unsigned short* wph  = (unsigned short*)(ws + 196 * MB);// 2 MB (alias wth, after k_kv)
    unsigned short* wpl  = (unsigned short*)(ws + 200 * MB);// 2 MB (alias wtl, after k_kv)
    float*          Vb   = (float*)d_out;                   // scratch until k_proj

    k_trig  <<<dim3(1024),     dim3(256), 0, stream>>>(tbl);
    k_cvtA  <<<dim3(16384),    dim3(256), 0, stream>>>(x, xh, xl, xll);
    k_cvtB  <<<dim3(32, 16),   dim3(256), 0, stream>>>(W_attn, wth, wtl);
    k_cvtBQ <<<dim3(16, 16),   dim3(256), 0, stream>>>(W_attn, wqh, wql, wqll);
    k_q6    <<<dim3(8, 64),    dim3(512), 0, stream>>>(xh, xl, xll, wqh, wql, wqll, b_attn, tbl, Qb);
    k_kv    <<<dim3(8, 128),   dim3(512), 0, stream>>>(xh, xl, wth, wtl, b_attn, tbl, Kb, Vb);
    k_cvtP  <<<dim3(16, 16),   dim3(256), 0, stream>>>(W_proj, wph, wpl);
    k_bucket<<<dim3(4096),     dim3(64),  0, stream>>>(Qb, R, bidx);
    k_sort  <<<dim3(64),       dim3(64),  0, stream>>>(bidx, sidx);
    k_attn  <<<dim3(32, 64),   dim3(256), 0, stream>>>(Qb, Kb, Vb, sidx, AOh, AOl);
    k_proj  <<<dim3(8, 64),    dim3(512), 0, stream>>>(AOh, AOl, wph, wpl, b_proj, out);
}

// Round 9
// 773.935 us; speedup vs baseline: 1.2438x; 1.2438x over previous
//
#include <hip/hip_runtime.h>
#include <math.h>

#define Bz 4
#define Tz 4096
#define Dz 1024
#define Hz 16
#define HDz 64
#define BHz 64
#define Mz 16384

typedef __attribute__((ext_vector_type(8))) short short8;
typedef __attribute__((ext_vector_type(8))) __bf16 bf16x8;
typedef __attribute__((ext_vector_type(4))) float floatx4;

__device__ inline unsigned short f2bf(float f) {
    unsigned u = __float_as_uint(f);
    u = (u + 0x7fffu + ((u >> 16) & 1u)) >> 16;   // RNE; finite data only
    return (unsigned short)u;
}
__device__ inline float bf2f(unsigned short h) {
    return __uint_as_float(((unsigned)h) << 16);
}

// async global->LDS 16B DMA; LDS dest must be wave-linear (base + lane*16)
__device__ __forceinline__ void g2l16(const void* g, void* l) {
    __builtin_amdgcn_global_load_lds(
        (const __attribute__((address_space(1))) unsigned int*)g,
        (__attribute__((address_space(3))) unsigned int*)l,
        16, 0, 0);
}

// ---------------- trig table (one (t,j) pair per thread) ----------------
__global__ __launch_bounds__(256) void k_trig(float* __restrict__ tbl) {
    int gid = blockIdx.x * 256 + threadIdx.x;   // 0..262143
    int t = gid >> 6;
    int j = gid & 63;
    int kidx = (j < 32) ? j : (j - 32);
    double e = (double)(2 * kidx) / 64.0;
    float p = (float)pow(10000.0, e);
    float invf = 1.0f / p;
    float arg = (float)t * invf;
    tbl[t * 128 + j * 2 + 0] = cosf(arg);
    tbl[t * 128 + j * 2 + 1] = sinf(arg);
}

// ---------------- split fp32 x -> bf16 3 levels ----------------
__global__ __launch_bounds__(256) void k_cvtA(const float* __restrict__ x,
                                              unsigned short* __restrict__ xh,
                                              unsigned short* __restrict__ xl,
                                              unsigned short* __restrict__ xll)
{
    size_t i4 = (size_t)blockIdx.x * 256 + threadIdx.x;
    float4 v = *(const float4*)(x + i4 * 4);
    ushort4 h, l, l2;
    float r;
    h.x = f2bf(v.x); r = v.x - bf2f(h.x); l.x = f2bf(r); l2.x = f2bf(r - bf2f(l.x));
    h.y = f2bf(v.y); r = v.y - bf2f(h.y); l.y = f2bf(r); l2.y = f2bf(r - bf2f(l.y));
    h.z = f2bf(v.z); r = v.z - bf2f(h.z); l.z = f2bf(r); l2.z = f2bf(r - bf2f(l.z));
    h.w = f2bf(v.w); r = v.w - bf2f(h.w); l.w = f2bf(r); l2.w = f2bf(r - bf2f(l.w));
    *(ushort4*)(xh  + i4 * 4) = h;
    *(ushort4*)(xl  + i4 * 4) = l;
    *(ushort4*)(xll + i4 * 4) = l2;
}

// ---------------- transpose+split W_attn K/V cols (2-level) ----------------
__global__ __launch_bounds__(256) void k_cvtB(const float* __restrict__ W,
                                              unsigned short* __restrict__ wh,
                                              unsigned short* __restrict__ wl)
{
    __shared__ float tile[64][65];
    const int n0 = blockIdx.x * 64;
    const int k0 = blockIdx.y * 64;
    const int tid = threadIdx.x;
#pragma unroll
    for (int i = 0; i < 16; ++i) {
        int flat = i * 256 + tid;
        int kr = flat >> 6, nc = flat & 63;
        tile[kr][nc] = W[(size_t)(k0 + kr) * 3072 + 1024 + n0 + nc];
    }
    __syncthreads();
#pragma unroll
    for (int i = 0; i < 16; ++i) {
        int flat = i * 256 + tid;
        int nr = flat >> 6, kc = flat & 63;
        float v = tile[kc][nr];
        unsigned short h = f2bf(v);
        wh[(size_t)(n0 + nr) * 1024 + k0 + kc] = h;
        wl[(size_t)(n0 + nr) * 1024 + k0 + kc] = f2bf(v - bf2f(h));
    }
}

// ---------------- transpose+split W_attn Q cols (3-level) ----------------
__global__ __launch_bounds__(256) void k_cvtBQ(const float* __restrict__ W,
                                               unsigned short* __restrict__ wh,
                                               unsigned short* __restrict__ wl,
                                               unsigned short* __restrict__ wll)
{
    __shared__ float tile[64][65];
    const int n0 = blockIdx.x * 64;
    const int k0 = blockIdx.y * 64;
    const int tid = threadIdx.x;
#pragma unroll
    for (int i = 0; i < 16; ++i) {
        int flat = i * 256 + tid;
        int kr = flat >> 6, nc = flat & 63;
        tile[kr][nc] = W[(size_t)(k0 + kr) * 3072 + n0 + nc];
    }
    __syncthreads();
#pragma unroll
    for (int i = 0; i < 16; ++i) {
        int flat = i * 256 + tid;
        int nr = flat >> 6, kc = flat & 63;
        float v = tile[kc][nr];
        unsigned short h = f2bf(v);
        float r1 = v - bf2f(h);
        unsigned short l = f2bf(r1);
        wh [(size_t)(n0 + nr) * 1024 + k0 + kc] = h;
        wl [(size_t)(n0 + nr) * 1024 + k0 + kc] = l;
        wll[(size_t)(n0 + nr) * 1024 + k0 + kc] = f2bf(r1 - bf2f(l));
    }
}

// ---------------- transpose+split W_proj ----------------
__global__ __launch_bounds__(256) void k_cvtP(const float* __restrict__ W,
                                              unsigned short* __restrict__ wh,
                                              unsigned short* __restrict__ wl)
{
    __shared__ float tile[64][65];
    const int n0 = blockIdx.x * 64;
    const int k0 = blockIdx.y * 64;
    const int tid = threadIdx.x;
#pragma unroll
    for (int i = 0; i < 16; ++i) {
        int flat = i * 256 + tid;
        int kr = flat >> 6, nc = flat & 63;
        tile[kr][nc] = W[(size_t)(k0 + kr) * 1024 + n0 + nc];
    }
    __syncthreads();
#pragma unroll
    for (int i = 0; i < 16; ++i) {
        int flat = i * 256 + tid;
        int nr = flat >> 6, kc = flat & 63;
        float v = tile[kc][nr];
        unsigned short h = f2bf(v);
        wh[(size_t)(n0 + nr) * 1024 + k0 + kc] = h;
        wl[(size_t)(n0 + nr) * 1024 + k0 + kc] = f2bf(v - bf2f(h));
    }
}

// ---------------- Q via 6-term split-bf16 MFMA (round-7 proven) -----------
__global__ __launch_bounds__(256) void k_q6(const unsigned short* __restrict__ xh,
                                            const unsigned short* __restrict__ xl,
                                            const unsigned short* __restrict__ xll,
                                            const unsigned short* __restrict__ wh,
                                            const unsigned short* __restrict__ wl,
                                            const unsigned short* __restrict__ wll,
                                            const float* __restrict__ bias,
                                            const float* __restrict__ tbl,
                                            float* __restrict__ Qb)
{
    __shared__ unsigned short Ah[128 * 32], Al[128 * 32], A2[128 * 32];
    __shared__ unsigned short Bh[128 * 32], Bl[128 * 32], B2[128 * 32];
    const int tid = threadIdx.x;
    const int lane = tid & 63, wv = tid >> 6;
    const int hw = blockIdx.y * 8 + blockIdx.x;      // nwg = 1024
    const int lg = (hw & 7) * 128 + (hw >> 3);       // bijective XCD-chunk
    const int n0 = (lg & 7) * 128;
    const int m0 = (lg >> 3) * 128;
    const int wm = (wv & 1) * 64, wn = (wv >> 1) * 64;
    const int sr = tid >> 2, sc = tid & 3;
    const int fr = lane & 15, fq = lane >> 4;

    floatx4 acc[4][4];
#pragma unroll
    for (int i = 0; i < 4; ++i)
#pragma unroll
        for (int j = 0; j < 4; ++j) acc[i][j] = (floatx4){0.f, 0.f, 0.f, 0.f};

    for (int kt = 0; kt < 1024; kt += 32) {
        __syncthreads();
#pragma unroll
        for (int s = 0; s < 2; ++s) {
            int row = s * 64 + sr;
            size_t ga = (size_t)(m0 + row) * 1024 + kt + sc * 8;
            size_t gb = (size_t)(n0 + row) * 1024 + kt + sc * 8;
            int lo = row * 32 + sc * 8;           // bytes = tid*16 within wave
            g2l16(xh  + ga, &Ah[lo]);
            g2l16(xl  + ga, &Al[lo]);
            g2l16(xll + ga, &A2[lo]);
            g2l16(wh  + gb, &Bh[lo]);
            g2l16(wl  + gb, &Bl[lo]);
            g2l16(wll + gb, &B2[lo]);
        }
        __syncthreads();

        bf16x8 a0[4], a1[4], a2[4];
#pragma unroll
        for (int i = 0; i < 4; ++i) {
            a0[i] = __builtin_bit_cast(bf16x8, *(const short8*)(&Ah[(wm + i * 16 + fr) * 32 + fq * 8]));
            a1[i] = __builtin_bit_cast(bf16x8, *(const short8*)(&Al[(wm + i * 16 + fr) * 32 + fq * 8]));
            a2[i] = __builtin_bit_cast(bf16x8, *(const short8*)(&A2[(wm + i * 16 + fr) * 32 + fq * 8]));
        }
#pragma unroll
        for (int j = 0; j < 4; ++j) {
            bf16x8 b0 = __builtin_bit_cast(bf16x8, *(const short8*)(&Bh[(wn + j * 16 + fr) * 32 + fq * 8]));
            bf16x8 b1 = __builtin_bit_cast(bf16x8, *(const short8*)(&Bl[(wn + j * 16 + fr) * 32 + fq * 8]));
            bf16x8 b2 = __builtin_bit_cast(bf16x8, *(const short8*)(&B2[(wn + j * 16 + fr) * 32 + fq * 8]));
#pragma unroll
            for (int i = 0; i < 4; ++i) {
                acc[i][j] = __builtin_amdgcn_mfma_f32_16x16x32_bf16(a0[i], b0, acc[i][j], 0, 0, 0);
                acc[i][j] = __builtin_amdgcn_mfma_f32_16x16x32_bf16(a0[i], b1, acc[i][j], 0, 0, 0);
                acc[i][j] = __builtin_amdgcn_mfma_f32_16x16x32_bf16(a1[i], b0, acc[i][j], 0, 0, 0);
                acc[i][j] = __builtin_amdgcn_mfma_f32_16x16x32_bf16(a1[i], b1, acc[i][j], 0, 0, 0);
                acc[i][j] = __builtin_amdgcn_mfma_f32_16x16x32_bf16(a0[i], b2, acc[i][j], 0, 0, 0);
                acc[i][j] = __builtin_amdgcn_mfma_f32_16x16x32_bf16(a2[i], b0, acc[i][j], 0, 0, 0);
            }
        }
    }

    // epilogue: bias + rope, scatter to Qb (all cols are Q)
#pragma unroll
    for (int j = 0; j < 4; ++j) {
        int nn = n0 + wn + j * 16 + fr;
        float bv = bias[nn];
        int h = nn >> 6, d = nn & 63;
#pragma unroll
        for (int i = 0; i < 4; ++i) {
#pragma unroll
            for (int r = 0; r < 4; ++r) {
                int mm = m0 + wm + i * 16 + fq * 4 + r;
                int t = mm & 4095, bb = mm >> 12;
                float y = acc[i][j][r] + bv;
                float part = __shfl_xor(y, 1);
                float c = tbl[t * 128 + d * 2];
                float s = tbl[t * 128 + d * 2 + 1];
                float o = (d & 1) ? fmaf(part, s, y * c) : fmaf(-part, s, y * c);
                Qb[((size_t)(bb * 16 + h) * 4096 + t) * 64 + d] = o;
            }
        }
    }
}

// ---------------- K,V GEMM (round-7 proven) + bf16 K/V handoff ------------
// K stored as bf16 hi/lo, V as bf16 — exact same f2bf chain k_attn used, so
// attn's staged values are bit-identical; V traffic halves.
__global__ __launch_bounds__(256) void k_kv(const unsigned short* __restrict__ xh,
                                            const unsigned short* __restrict__ xl,
                                            const unsigned short* __restrict__ wh,
                                            const unsigned short* __restrict__ wl,
                                            const float* __restrict__ bias,
                                            const float* __restrict__ tbl,
                                            unsigned short* __restrict__ Khb,
                                            unsigned short* __restrict__ Klb,
                                            unsigned short* __restrict__ Vhb)
{
    __shared__ unsigned short Ah[128 * 32], Al[128 * 32], Bh[128 * 32], Bl[128 * 32];
    const int tid = threadIdx.x;
    const int lane = tid & 63, wv = tid >> 6;
    const int hw = blockIdx.y * 16 + blockIdx.x;     // nwg = 2048
    const int lg = (hw & 7) * 256 + (hw >> 3);       // bijective XCD-chunk
    const int n0 = (lg & 15) * 128;
    const int m0 = (lg >> 4) * 128;
    const int wm = (wv & 1) * 64, wn = (wv >> 1) * 64;
    const int sr = tid >> 2, sc = tid & 3;
    const int fr = lane & 15, fq = lane >> 4;

    floatx4 acc[4][4];
#pragma unroll
    for (int i = 0; i < 4; ++i)
#pragma unroll
        for (int j = 0; j < 4; ++j) acc[i][j] = (floatx4){0.f, 0.f, 0.f, 0.f};

    for (int kt = 0; kt < 1024; kt += 32) {
        __syncthreads();
#pragma unroll
        for (int s = 0; s < 2; ++s) {
            int row = s * 64 + sr;
            size_t ga = (size_t)(m0 + row) * 1024 + kt + sc * 8;
            size_t gb = (size_t)(n0 + row) * 1024 + kt + sc * 8;
            int lo = row * 32 + sc * 8;           // bytes = tid*16 within wave
            g2l16(xh + ga, &Ah[lo]);
            g2l16(xl + ga, &Al[lo]);
            g2l16(wh + gb, &Bh[lo]);
            g2l16(wl + gb, &Bl[lo]);
        }
        __syncthreads();

        bf16x8 afh[4], afl[4], bfh[4], bfl[4];
#pragma unroll
        for (int i = 0; i < 4; ++i) {
            afh[i] = __builtin_bit_cast(bf16x8, *(const short8*)(&Ah[(wm + i * 16 + fr) * 32 + fq * 8]));
            afl[i] = __builtin_bit_cast(bf16x8, *(const short8*)(&Al[(wm + i * 16 + fr) * 32 + fq * 8]));
            bfh[i] = __builtin_bit_cast(bf16x8, *(const short8*)(&Bh[(wn + i * 16 + fr) * 32 + fq * 8]));
            bfl[i] = __builtin_bit_cast(bf16x8, *(const short8*)(&Bl[(wn + i * 16 + fr) * 32 + fq * 8]));
        }
#pragma unroll
        for (int i = 0; i < 4; ++i)
#pragma unroll
            for (int j = 0; j < 4; ++j) {
                acc[i][j] = __builtin_amdgcn_mfma_f32_16x16x32_bf16(afh[i], bfh[j], acc[i][j], 0, 0, 0);
                acc[i][j] = __builtin_amdgcn_mfma_f32_16x16x32_bf16(afh[i], bfl[j], acc[i][j], 0, 0, 0);
                acc[i][j] = __builtin_amdgcn_mfma_f32_16x16x32_bf16(afl[i], bfh[j], acc[i][j], 0, 0, 0);
            }
    }

#pragma unroll
    for (int j = 0; j < 4; ++j) {
        int nn = n0 + wn + j * 16 + fr;
        float bv = bias[1024 + nn];
#pragma unroll
        for (int i = 0; i < 4; ++i) {
#pragma unroll
            for (int r = 0; r < 4; ++r) {
                int mm = m0 + wm + i * 16 + fq * 4 + r;
                int t = mm & 4095, bb = mm >> 12;
                float y = acc[i][j][r] + bv;
                if (nn < 1024) {
                    int h = nn >> 6, d = nn & 63;
                    float part = __shfl_xor(y, 1);
                    float c = tbl[t * 128 + d * 2];
                    float s = tbl[t * 128 + d * 2 + 1];
                    float o = (d & 1) ? fmaf(part, s, y * c) : fmaf(-part, s, y * c);
                    unsigned short oh = f2bf(o);
                    unsigned short ol = f2bf(o - bf2f(oh));
                    size_t idx = ((size_t)(bb * 16 + h) * 4096 + t) * 64 + d;
                    Khb[idx] = oh;
                    Klb[idx] = ol;
                } else {
                    int nv = nn - 1024;
                    int h = nv >> 6, d = nv & 63;
                    Vhb[((size_t)(bb * 16 + h) * 4096 + t) * 64 + d] = f2bf(y);
                }
            }
        }
    }
}

// ---------------- bucket argmax ----------------
__global__ __launch_bounds__(64) void k_bucket(const float* __restrict__ Q,
                                               const float* __restrict__ R,
                                               int* __restrict__ bidx)
{
    __shared__ float Qs[64][65];
    __shared__ float Rs[64][32];
    const int tid = threadIdx.x;
    const int g0 = blockIdx.x * 64;
    const int bh = g0 >> 12;
    const int t0 = g0 & 4095;
#pragma unroll
    for (int m = 0; m < 32; ++m) Rs[tid][m] = R[tid * 64 + m];
    const float* qbase = Q + ((size_t)bh * Tz + t0) * 64;
    for (int r = 0; r < 64; ++r) Qs[r][tid] = qbase[(size_t)r * 64 + tid];
    __syncthreads();

    float s[32];
#pragma unroll
    for (int m = 0; m < 32; ++m) s[m] = 0.f;
    for (int d = 0; d < 64; ++d) {
        float qd = Qs[tid][d];
#pragma unroll
        for (int m4 = 0; m4 < 8; ++m4) {
            float4 r4 = *(const float4*)(&Rs[d][m4 * 4]);
            s[m4 * 4 + 0] = fmaf(qd, r4.x, s[m4 * 4 + 0]);
            s[m4 * 4 + 1] = fmaf(qd, r4.y, s[m4 * 4 + 1]);
            s[m4 * 4 + 2] = fmaf(qd, r4.z, s[m4 * 4 + 2]);
            s[m4 * 4 + 3] = fmaf(qd, r4.w, s[m4 * 4 + 3]);
        }
    }
    float best = s[0];
    int bi = 0;
#pragma unroll
    for (int m = 1; m < 64; ++m) {
        float v = (m < 32) ? s[m] : -s[m - 32];
        if (v > best) { best = v; bi = m; }
    }
    bidx[g0 + tid] = bi;
}

// ---------------- stable counting sort, wave-parallel ballot ranking ------
__global__ __launch_bounds__(64) void k_sort(const int* __restrict__ bidx,
                                             int* __restrict__ sidx)
{
    __shared__ int lb[4096];      // keys, then reused as packed (k<<16)|off
    __shared__ int ls[4096];
    __shared__ int runTot[64];
    __shared__ int base[64];
    const int lane = threadIdx.x;
    const int bh = blockIdx.x;
    const int* brow = bidx + (size_t)bh * 4096;
    for (int i = lane; i < 4096; i += 64) lb[i] = brow[i];
    runTot[lane] = 0;
    // single-wave kernel: LDS ops of one wave execute in program order

    const unsigned long long lmask = (1ull << lane) - 1ull;
    for (int r = 0; r < 64; ++r) {
        int i = r * 64 + lane;
        int k = lb[i];
        unsigned long long m = ~0ull;
#pragma unroll
        for (int b = 0; b < 6; ++b) {
            unsigned long long bb = __ballot((k >> b) & 1);
            m &= ((k >> b) & 1) ? bb : ~bb;
        }
        int rank = __popcll(m & lmask);
        int before = runTot[k];              // all lanes read pre-update value
        lb[i] = (k << 16) | (before + rank); // pack key + local offset
        if (rank == 0) runTot[k] = before + __popcll(m);
    }
    // exclusive prefix over 64 buckets (lane b holds bucket b)
    int tot = runTot[lane];
    int run = tot;
#pragma unroll
    for (int off = 1; off < 64; off <<= 1) {
        int n = __shfl_up(run, off, 64);
        if (lane >= off) run += n;
    }
    base[lane] = run - tot;
    // scatter
    for (int r = 0; r < 64; ++r) {
        int i = r * 64 + lane;
        int v = lb[i];
        ls[base[v >> 16] + (v & 0xffff)] = i;
    }
    int* srow = sidx + (size_t)bh * 4096;
    for (int i = lane; i < 4096; i += 64) srow[i] = ls[i];
}

// ---------------- chunked attention via MFMA (bf16 K/V inputs) -----------
// LDS (ushort): Kh[128][72]@0, Kl[128][72]@9216 ; P[128][144] overlays @0 after S
//               Vt[64][144]@18432  (dim-major)   total 27648 us = 55296 B
__global__ __launch_bounds__(256) void k_attn(const float* __restrict__ Q,
                                              const unsigned short* __restrict__ Khb,
                                              const unsigned short* __restrict__ Klb,
                                              const unsigned short* __restrict__ Vhb,
                                              const int* __restrict__ sidx,
                                              unsigned short* __restrict__ AOh,
                                              unsigned short* __restrict__ AOl)
{
    __shared__ unsigned short smem[27648];
    unsigned short* KhS = smem;
    unsigned short* KlS = smem + 9216;
    unsigned short* PbS = smem;
    unsigned short* VtS = smem + 18432;

    // XCD-chunked swizzle: all 32 chunks of one bh land on one XCD
    const int hw = blockIdx.y * 32 + blockIdx.x;     // nwg = 2048
    const int lg = (hw & 7) * 256 + (hw >> 3);
    const int ch = lg & 31;
    const int bh = lg >> 5;
    const int tid = threadIdx.x;
    const int lane = tid & 63;
    const int w = tid >> 6;
    const int c = lane & 15;   // frag row/col
    const int q = lane >> 4;   // quad
    const int* srow = sidx + (size_t)bh * Tz + ch * 128;

    // ---- stage K (pre-split bf16 hi/lo) and V^T (pre-converted bf16) ----
    {
        const int r = tid >> 1;
        const int d0 = (tid & 1) * 32;
        int orig = srow[r];
        size_t kb = ((size_t)bh * Tz + orig) * 64 + d0;
        const unsigned short* khp = Khb + kb;
        const unsigned short* klp = Klb + kb;
        const unsigned short* vhp = Vhb + kb;
#pragma unroll
        for (int j8 = 0; j8 < 4; ++j8) {
            *(short8*)(&KhS[r * 72 + d0 + j8 * 8]) = *(const short8*)(khp + j8 * 8);
            *(short8*)(&KlS[r * 72 + d0 + j8 * 8]) = *(const short8*)(klp + j8 * 8);
            short8 v8 = *(const short8*)(vhp + j8 * 8);
            int db = d0 + j8 * 8;
#pragma unroll
            for (int e = 0; e < 8; ++e)
                VtS[(db + e) * 144 + r] = (unsigned short)v8[e];
        }
    }

    // ---- Q fragments from global into registers (bf16 hi/lo) ----
    bf16x8 qh[2][2], ql[2][2];
#pragma unroll
    for (int i = 0; i < 2; ++i) {
        int row = w * 32 + i * 16 + c;
        int orig = srow[row];
        const float* qp = Q + ((size_t)bh * Tz + orig) * 64 + q * 8;
#pragma unroll
        for (int kc = 0; kc < 2; ++kc) {
            float4 fa = *(const float4*)(qp + kc * 32);
            float4 fb = *(const float4*)(qp + kc * 32 + 4);
            float f[8] = {fa.x, fa.y, fa.z, fa.w, fb.x, fb.y, fb.z, fb.w};
            short8 hh, ll;
#pragma unroll
            for (int e = 0; e < 8; ++e) {
                unsigned short h = f2bf(f[e]);
                hh[e] = (short)h;
                ll[e] = (short)f2bf(f[e] - bf2f(h));
            }
            qh[i][kc] = __builtin_bit_cast(bf16x8, hh);
            ql[i][kc] = __builtin_bit_cast(bf16x8, ll);
        }
    }
    __syncthreads();

    // ---- S = Q K^T (3-term split) ----
    floatx4 accs[2][8];
#pragma unroll
    for (int i = 0; i < 2; ++i)
#pragma unroll
        for (int j = 0; j < 8; ++j) accs[i][j] = (floatx4){0.f, 0.f, 0.f, 0.f};

#pragma unroll
    for (int j = 0; j < 8; ++j) {
        int n = j * 16 + c;
        bf16x8 kbh[2], kbl[2];
#pragma unroll
        for (int kc = 0; kc < 2; ++kc) {
            kbh[kc] = __builtin_bit_cast(bf16x8, *(const short8*)(&KhS[n * 72 + kc * 32 + q * 8]));
            kbl[kc] = __builtin_bit_cast(bf16x8, *(const short8*)(&KlS[n * 72 + kc * 32 + q * 8]));
        }
#pragma unroll
        for (int i = 0; i < 2; ++i)
#pragma unroll
            for (int kc = 0; kc < 2; ++kc) {
                accs[i][j] = __builtin_amdgcn_mfma_f32_16x16x32_bf16(qh[i][kc], kbh[kc], accs[i][j], 0, 0, 0);
                accs[i][j] = __builtin_amdgcn_mfma_f32_16x16x32_bf16(qh[i][kc], kbl[kc], accs[i][j], 0, 0, 0);
                accs[i][j] = __builtin_amdgcn_mfma_f32_16x16x32_bf16(ql[i][kc], kbh[kc], accs[i][j], 0, 0, 0);
            }
    }

    // ---- softmax over rows (row = w*32 + i*16 + q*4 + r) ----
    float linv[2][4];
#pragma unroll
    for (int i = 0; i < 2; ++i) {
#pragma unroll
        for (int r = 0; r < 4; ++r) {
            float mm = -1e30f;
#pragma unroll
            for (int j = 0; j < 8; ++j) {
                float v = accs[i][j][r] * 0.125f;
                accs[i][j][r] = v;
                mm = fmaxf(mm, v);
            }
#pragma unroll
            for (int off = 1; off < 16; off <<= 1) mm = fmaxf(mm, __shfl_xor(mm, off));
            float ss = 0.f;
#pragma unroll
            for (int j = 0; j < 8; ++j) {
                float p = expf(accs[i][j][r] - mm);
                accs[i][j][r] = p;
                ss += p;
            }
#pragma unroll
            for (int off = 1; off < 16; off <<= 1) ss += __shfl_xor(ss, off);
            linv[i][r] = 1.0f / ss;
        }
    }
    __syncthreads();   // all K reads done; safe to overlay P

    // ---- write P (bf16) rows [w*32, w*32+32) ----
#pragma unroll
    for (int i = 0; i < 2; ++i)
#pragma unroll
        for (int j = 0; j < 8; ++j)
#pragma unroll
            for (int r = 0; r < 4; ++r)
                PbS[(w * 32 + i * 16 + q * 4 + r) * 144 + j * 16 + c] = f2bf(accs[i][j][r]);
    // own-rows only: no barrier needed (same-wave write->read ordering via lgkmcnt)

    // ---- O = P V ----
    floatx4 acco[2][4];
#pragma unroll
    for (int i = 0; i < 2; ++i)
#pragma unroll
        for (int jf = 0; jf < 4; ++jf) acco[i][jf] = (floatx4){0.f, 0.f, 0.f, 0.f};

#pragma unroll
    for (int kc = 0; kc < 4; ++kc) {
        bf16x8 pa[2];
#pragma unroll
        for (int i = 0; i < 2; ++i)
            pa[i] = __builtin_bit_cast(bf16x8, *(const short8*)(&PbS[(w * 32 + i * 16 + c) * 144 + kc * 32 + q * 8]));
#pragma unroll
        for (int jf = 0; jf < 4; ++jf) {
            bf16x8 vb = __builtin_bit_cast(bf16x8, *(const short8*)(&VtS[(jf * 16 + c) * 144 + kc * 32 + q * 8]));
            acco[0][jf] = __builtin_amdgcn_mfma_f32_16x16x32_bf16(pa[0], vb, acco[0][jf], 0, 0, 0);
            acco[1][jf] = __builtin_amdgcn_mfma_f32_16x16x32_bf16(pa[1], vb, acco[1][jf], 0, 0, 0);
        }
    }

    // ---- epilogue: normalize, split bf16, scatter-unsort ----
    const int bb = bh >> 4, hh = bh & 15;
#pragma unroll
    for (int i = 0; i < 2; ++i) {
#pragma unroll
        for (int r = 0; r < 4; ++r) {
            int row = w * 32 + i * 16 + q * 4 + r;
            int orig = srow[row];
            float inv = linv[i][r];
            size_t base = ((size_t)bb * 4096 + orig) * 1024 + hh * 64 + c;
#pragma unroll
            for (int jf = 0; jf < 4; ++jf) {
                float val = acco[i][jf][r] * inv;
                unsigned short h = f2bf(val);
                unsigned short l = f2bf(val - bf2f(h));
                AOh[base + jf * 16] = h;
                AOl[base + jf * 16] = l;
            }
        }
    }
}

// ---------------- output projection (round-7 proven) ----------------
__global__ __launch_bounds__(256) void k_proj(const unsigned short* __restrict__ ah,
                                              const unsigned short* __restrict__ al,
                                              const unsigned short* __restrict__ wh,
                                              const unsigned short* __restrict__ wl,
                                              const float* __restrict__ bias,
                                              float* __restrict__ Cout)
{
    __shared__ unsigned short Ah[128 * 32], Al[128 * 32], Bh[128 * 32], Bl[128 * 32];
    const int tid = threadIdx.x;
    const int lane = tid & 63, wv = tid >> 6;
    const int hw = blockIdx.y * 8 + blockIdx.x;      // nwg = 1024
    const int lg = (hw & 7) * 128 + (hw >> 3);       // bijective XCD-chunk
    const int n0 = (lg & 7) * 128;
    const int m0 = (lg >> 3) * 128;
    const int wm = (wv & 1) * 64, wn = (wv >> 1) * 64;
    const int sr = tid >> 2, sc = tid & 3;
    const int fr = lane & 15, fq = lane >> 4;

    floatx4 acc[4][4];
#pragma unroll
    for (int i = 0; i < 4; ++i)
#pragma unroll
        for (int j = 0; j < 4; ++j) acc[i][j] = (floatx4){0.f, 0.f, 0.f, 0.f};

    for (int kt = 0; kt < 1024; kt += 32) {
        __syncthreads();
#pragma unroll
        for (int s = 0; s < 2; ++s) {
            int row = s * 64 + sr;
            size_t ga = (size_t)(m0 + row) * 1024 + kt + sc * 8;
            size_t gb = (size_t)(n0 + row) * 1024 + kt + sc * 8;
            int lo = row * 32 + sc * 8;           // bytes = tid*16 within wave
            g2l16(ah + ga, &Ah[lo]);
            g2l16(al + ga, &Al[lo]);
            g2l16(wh + gb, &Bh[lo]);
            g2l16(wl + gb, &Bl[lo]);
        }
        __syncthreads();

        bf16x8 afh[4], afl[4], bfh[4], bfl[4];
#pragma unroll
        for (int i = 0; i < 4; ++i) {
            afh[i] = __builtin_bit_cast(bf16x8, *(const short8*)(&Ah[(wm + i * 16 + fr) * 32 + fq * 8]));
            afl[i] = __builtin_bit_cast(bf16x8, *(const short8*)(&Al[(wm + i * 16 + fr) * 32 + fq * 8]));
            bfh[i] = __builtin_bit_cast(bf16x8, *(const short8*)(&Bh[(wn + i * 16 + fr) * 32 + fq * 8]));
            bfl[i] = __builtin_bit_cast(bf16x8, *(const short8*)(&Bl[(wn + i * 16 + fr) * 32 + fq * 8]));
        }
#pragma unroll
        for (int i = 0; i < 4; ++i)
#pragma unroll
            for (int j = 0; j < 4; ++j) {
                acc[i][j] = __builtin_amdgcn_mfma_f32_16x16x32_bf16(afh[i], bfh[j], acc[i][j], 0, 0, 0);
                acc[i][j] = __builtin_amdgcn_mfma_f32_16x16x32_bf16(afh[i], bfl[j], acc[i][j], 0, 0, 0);
                acc[i][j] = __builtin_amdgcn_mfma_f32_16x16x32_bf16(afl[i], bfh[j], acc[i][j], 0, 0, 0);
            }
    }

#pragma unroll
    for (int j = 0; j < 4; ++j) {
        int nn = n0 + wn + j * 16 + fr;
        float bv = bias[nn];
#pragma unroll
        for (int i = 0; i < 4; ++i) {
#pragma unroll
            for (int r = 0; r < 4; ++r) {
                int mm = m0 + wm + i * 16 + fq * 4 + r;
                Cout[(size_t)mm * 1024 + nn] = acc[i][j][r] + bv;
            }
        }
    }
}

extern "C" void kernel_launch(void* const* d_in, const int* in_sizes, int n_in,
                              void* d_out, int out_size, void* d_ws, size_t ws_size,
                              hipStream_t stream)
{
    const float* x      = (const float*)d_in[0];
    const float* W_attn = (const float*)d_in[1];
    const float* b_attn = (const float*)d_in[2];
    const float* W_proj = (const float*)d_in[3];
    const float* b_proj = (const float*)d_in[4];
    const float* R      = (const float*)d_in[5];
    float* out = (float*)d_out;

    char* ws = (char*)d_ws;
    const size_t MB = 1024 * 1024;
    float*          tbl  = (float*)(ws);                    // 0-2 MB
    float*          Qb   = (float*)(ws + 2 * MB);           // 2-66 MB
    unsigned short* Khb  = (unsigned short*)(ws + 66 * MB); // 66-98 MB
    unsigned short* Klb  = (unsigned short*)(ws + 98 * MB); // 98-130 MB
    // Q-GEMM-only buffers alias the Khb/Klb region (consumed before k_kv)
    unsigned short* xll  = (unsigned short*)(ws + 66 * MB); // 66-98 MB  (alias Khb)
    unsigned short* wqh  = (unsigned short*)(ws + 98 * MB); // 98-100 MB (alias Klb)
    unsigned short* wql  = (unsigned short*)(ws + 100 * MB);// 100-102 MB(alias Klb)
    unsigned short* wqll = (unsigned short*)(ws + 102 * MB);// 102-104 MB(alias Klb)
    unsigned short* xh   = (unsigned short*)(ws + 130 * MB);// 32 MB
    unsigned short* xl   = (unsigned short*)(ws + 162 * MB);// 32 MB
    unsigned short* AOh  = (unsigned short*)(ws + 130 * MB);// 32 MB (alias xh)
    unsigned short* AOl  = (unsigned short*)(ws + 162 * MB);// 32 MB (alias xl)
    int*            bidx = (int*)(ws + 194 * MB);           // 1 MB
    int*            sidx = (int*)(ws + 195 * MB);           // 1 MB
    unsigned short* wth  = (unsigned short*)(ws + 196 * MB);// 4 MB
    unsigned short* wtl  = (unsigned short*)(ws + 200 * MB);// 4 MB
    unsigned short* wph  = (unsigned short*)(ws + 196 * MB);// 2 MB (alias wth, after k_kv)
    unsigned short* wpl  = (unsigned short*)(ws + 200 * MB);// 2 MB (alias wtl, after k_kv)
    unsigned short* Vhb  = (unsigned short*)d_out;          // 32 MB scratch until k_proj

    k_trig  <<<dim3(1024),     dim3(256), 0, stream>>>(tbl);
    k_cvtA  <<<dim3(16384),    dim3(256), 0, stream>>>(x, xh, xl, xll);
    k_cvtB  <<<dim3(32, 16),   dim3(256), 0, stream>>>(W_attn, wth, wtl);
    k_cvtBQ <<<dim3(16, 16),   dim3(256), 0, stream>>>(W_attn, wqh, wql, wqll);
    k_q6    <<<dim3(8, 128),   dim3(256), 0, stream>>>(xh, xl, xll, wqh, wql, wqll, b_attn, tbl, Qb);
    k_kv    <<<dim3(16, 128),  dim3(256), 0, stream>>>(xh, xl, wth, wtl, b_attn, tbl, Khb, Klb, Vhb);
    k_cvtP  <<<dim3(16, 16),   dim3(256), 0, stream>>>(W_proj, wph, wpl);
    k_bucket<<<dim3(4096),     dim3(64),  0, stream>>>(Qb, R, bidx);
    k_sort  <<<dim3(64),       dim3(64),  0, stream>>>(bidx, sidx);
    k_attn  <<<dim3(32, 64),   dim3(256), 0, stream>>>(Qb, Khb, Klb, Vhb, sidx, AOh, AOl);
    k_proj  <<<dim3(8, 128),   dim3(256), 0, stream>>>(AOh, AOl, wph, wpl, b_proj, out);
}